// Round 1
// baseline (1035.296 us; speedup 1.0000x reference)
//
#include <hip/hip_runtime.h>
#include <hip/hip_bf16.h>
#include <math.h>

#define BB 4
#define SS 1024
#define HH 768
#define NHEAD 12
#define NN 32
#define MM 4
#define WD 768
#define AD 256
#define NC 97
#define SPK 64
#define DD 12

// ---------------- rep: logsumexp over mentions ----------------
__global__ void k_rep(const float* __restrict__ seq, const int* __restrict__ ep,
                      float* __restrict__ rep) {
  int bn = blockIdx.x; int b = bn / NN;
  const int* e = ep + (size_t)bn * MM;
  int i0 = e[0], i1 = e[1], i2 = e[2], i3 = e[3];
  const float* sb = seq + (size_t)b * SS * HH;
  for (int h = threadIdx.x; h < HH; h += blockDim.x) {
    float v0 = sb[(size_t)i0 * HH + h];
    float v1 = sb[(size_t)i1 * HH + h];
    float v2 = sb[(size_t)i2 * HH + h];
    float v3 = sb[(size_t)i3 * HH + h];
    float mx = fmaxf(fmaxf(v0, v1), fmaxf(v2, v3));
    float s = expf(v0 - mx) + expf(v1 - mx) + expf(v2 - mx) + expf(v3 - mx);
    rep[(size_t)bn * HH + h] = mx + logf(s);
  }
}

// ---------------- ga: sum of mention attention rows ----------------
__global__ void k_ga(const float* __restrict__ att, const int* __restrict__ ep,
                     float* __restrict__ ga) {
  int t = blockIdx.x;
  int h = t % NHEAD;
  int bn = t / NHEAD;
  int b = bn / NN;
  const int* e = ep + (size_t)bn * MM;
  int i0 = e[0], i1 = e[1], i2 = e[2], i3 = e[3];
  const float* ab = att + ((size_t)b * NHEAD + h) * SS * SS;
  float* go = ga + ((size_t)bn * NHEAD + h) * SS;
  for (int s = threadIdx.x; s < SS; s += blockDim.x) {
    go[s] = ab[(size_t)i0 * SS + s] + ab[(size_t)i1 * SS + s] +
            ab[(size_t)i2 * SS + s] + ab[(size_t)i3 * SS + s];
  }
}

// ---------------- pa: pairwise product over heads + normalize over s --------
__global__ __launch_bounds__(256) void k_pa(const float* __restrict__ ga,
                                            float* __restrict__ pa) {
  int t = blockIdx.x;               // b*N*N + i*N + j
  int j = t % NN;
  int i = (t / NN) % NN;
  int b = t / (NN * NN);
  const float* gi = ga + ((size_t)(b * NN + i)) * NHEAD * SS;
  const float* gj = ga + ((size_t)(b * NN + j)) * NHEAD * SS;
  float acc[4];
  float tot = 0.f;
#pragma unroll
  for (int r = 0; r < 4; ++r) {
    int s = threadIdx.x + r * 256;
    float a = 0.f;
#pragma unroll
    for (int h = 0; h < NHEAD; ++h) a += gi[h * SS + s] * gj[h * SS + s];
    acc[r] = a;
    tot += a;
  }
  __shared__ float red[256];
  red[threadIdx.x] = tot;
  __syncthreads();
  for (int o = 128; o > 0; o >>= 1) {
    if (threadIdx.x < o) red[threadIdx.x] += red[threadIdx.x + o];
    __syncthreads();
  }
  float inv = 1.0f / red[0];
  float* po = pa + (size_t)t * SS;
#pragma unroll
  for (int r = 0; r < 4; ++r) {
    int s = threadIdx.x + r * 256;
    po[s] = acc[r] * inv;
  }
}

// ---------------- generic fp32 tiled GEMM ----------------
// C[m,n] = sum_k A[m,k] * B[k,n]        (TRANS_B=0, B is [K,N])
// C[m,n] = sum_k A[m,k] * B[n,k]        (TRANS_B=1, B is [N,K])
// optional epilogue: C += biasScale * bias[n]
template <int TRANS_B>
__global__ __launch_bounds__(256)
void k_gemm(const float* __restrict__ A, const float* __restrict__ B,
            float* __restrict__ C, int Mr, int Nc, int Kd,
            long long sA, long long sB, long long sC,
            const float* __restrict__ bias, float biasScale) {
  A += (long long)blockIdx.z * sA;
  B += (long long)blockIdx.z * sB;
  C += (long long)blockIdx.z * sC;
  __shared__ float As[16][65];
  __shared__ float Bs[16][65];
  const int tid = threadIdx.x;
  const int tm = tid >> 4;  // 0..15
  const int tn = tid & 15;  // 0..15
  const int m0 = blockIdx.y * 64;
  const int n0 = blockIdx.x * 64;
  float acc[4][4] = {};
  for (int k0 = 0; k0 < Kd; k0 += 16) {
    {
      const int ak = tid & 15;
      const int am = tid >> 4;
#pragma unroll
      for (int c = 0; c < 4; ++c) {
        As[ak][am + 16 * c] = A[(size_t)(m0 + am + 16 * c) * Kd + k0 + ak];
      }
    }
    if (TRANS_B) {
      const int bk = tid & 15;
      const int bn = tid >> 4;
#pragma unroll
      for (int c = 0; c < 4; ++c) {
        int n = n0 + bn + 16 * c;
        Bs[bk][bn + 16 * c] = (n < Nc) ? B[(size_t)n * Kd + k0 + bk] : 0.0f;
      }
    } else {
      const int bn = tid & 63;
      const int bk = tid >> 6;
#pragma unroll
      for (int c = 0; c < 4; ++c) {
        int n = n0 + bn;
        Bs[bk + 4 * c][bn] = (n < Nc) ? B[(size_t)(k0 + bk + 4 * c) * Nc + n] : 0.0f;
      }
    }
    __syncthreads();
#pragma unroll
    for (int k = 0; k < 16; ++k) {
      float a[4], bv[4];
#pragma unroll
      for (int i = 0; i < 4; ++i) a[i] = As[k][tm + 16 * i];
#pragma unroll
      for (int j = 0; j < 4; ++j) bv[j] = Bs[k][tn + 16 * j];
#pragma unroll
      for (int i = 0; i < 4; ++i)
#pragma unroll
        for (int j = 0; j < 4; ++j) acc[i][j] += a[i] * bv[j];
    }
    __syncthreads();
  }
#pragma unroll
  for (int i = 0; i < 4; ++i) {
    int m = m0 + tm + 16 * i;
#pragma unroll
    for (int j = 0; j < 4; ++j) {
      int n = n0 + tn + 16 * j;
      if (n < Nc) {
        float v = acc[i][j];
        if (bias) v += biasScale * bias[n];
        C[(size_t)m * Nc + n] = v;
      }
    }
  }
}

// ---------------- Zs/Zo -> Gram matrix M (144 per pair) ----------------
__global__ __launch_bounds__(256) void k_M(const float* __restrict__ ctx,
                                           const float* __restrict__ rs,
                                           const float* __restrict__ ro,
                                           float* __restrict__ Mm) {
  int t = blockIdx.x;  // b*N*N + i*N + j
  int b = t / (NN * NN);
  int ij = t % (NN * NN);
  int i = ij / NN;
  __shared__ float zs[WD];
  __shared__ float zo[WD];
  const float* cx = ctx + (size_t)t * WD;
  const float* rsi = rs + ((size_t)(b * NN + i)) * WD;
  const float* roi = ro + ((size_t)(b * NN + i)) * WD;
  for (int w = threadIdx.x; w < WD; w += blockDim.x) {
    float c = cx[w];
    zs[w] = tanhf(rsi[w] + c);
    zo[w] = tanhf(roi[w] + c);
  }
  __syncthreads();
  int pq = threadIdx.x;
  if (pq < DD * DD) {
    int p = pq / DD, q = pq % DD;
    float s = 0.f;
#pragma unroll
    for (int k = 0; k < SPK; ++k) s += zs[p * SPK + k] * zo[q * SPK + k];
    Mm[(size_t)t * (DD * DD) + pq] = s;
  }
}

// ---------------- e = tanh(g@W_attn) @ v_attn (reduction part) -------------
__global__ __launch_bounds__(AD) void k_e(const float* __restrict__ tbuf,
                                          const float* __restrict__ v_attn,
                                          float* __restrict__ e) {
  int r = blockIdx.x;
  int a = threadIdx.x;
  float v = tanhf(tbuf[(size_t)r * AD + a]) * v_attn[a];
  __shared__ float red[AD];
  red[a] = v;
  __syncthreads();
  for (int o = AD / 2; o > 0; o >>= 1) {
    if (a < o) red[a] += red[a + o];
    __syncthreads();
  }
  if (a == 0) e[r] = red[0];
}

// ---------------- row/col softmax over the 32x32 pair grid -----------------
__global__ __launch_bounds__(1024) void k_softmax(const float* __restrict__ e,
                                                  float* __restrict__ arow,
                                                  float* __restrict__ acol) {
  int b = blockIdx.x;
  __shared__ float E[NN][NN + 1];
  __shared__ float Rm[NN], Rs[NN];
  int tid = threadIdx.x;
  int i = tid / NN, j = tid % NN;
  E[i][j] = e[(size_t)b * NN * NN + tid];
  __syncthreads();
  if (tid < NN) {
    float mx = -1e30f;
    for (int jj = 0; jj < NN; ++jj) mx = fmaxf(mx, E[tid][jj]);
    float s = 0.f;
    for (int jj = 0; jj < NN; ++jj) s += expf(E[tid][jj] - mx);
    Rm[tid] = mx;
    Rs[tid] = s;
  }
  __syncthreads();
  arow[(size_t)b * NN * NN + tid] = expf(E[i][j] - Rm[i]) / Rs[i];
  __syncthreads();
  if (tid < NN) {
    float mx = -1e30f;
    for (int ii = 0; ii < NN; ++ii) mx = fmaxf(mx, E[ii][tid]);
    float s = 0.f;
    for (int ii = 0; ii < NN; ++ii) s += expf(E[ii][tid] - mx);
    Rm[tid] = mx;
    Rs[tid] = s;
  }
  __syncthreads();
  acol[(size_t)b * NN * NN + tid] = expf(E[i][j] - Rm[j]) / Rs[j];
}

// ---------------- rowctx / colctx ----------------
__global__ __launch_bounds__(256) void k_rowcol(const float* __restrict__ g,
                                                const float* __restrict__ arow,
                                                const float* __restrict__ acol,
                                                float* __restrict__ rc) {
  int t = blockIdx.x;              // [0, 2*B*N)
  int which = t / (BB * NN);       // 0 = row, 1 = col
  int bn = t % (BB * NN);
  int b = bn / NN, x = bn % NN;
  const float* gb = g + (size_t)b * NN * NN * WD;
  float* out = rc + ((size_t)which * BB * NN + bn) * WD;
  for (int o = threadIdx.x; o < WD; o += blockDim.x) {
    float s = 0.f;
    if (which == 0) {
      const float* ar = arow + (size_t)b * NN * NN + (size_t)x * NN;
#pragma unroll 4
      for (int jj = 0; jj < NN; ++jj) s += ar[jj] * gb[((size_t)x * NN + jj) * WD + o];
    } else {
      const float* ac = acol + (size_t)b * NN * NN;
#pragma unroll 4
      for (int ii = 0; ii < NN; ++ii) s += ac[(size_t)ii * NN + x] * gb[((size_t)ii * NN + x) * WD + o];
    }
    out[o] = s;
  }
}

// ---------------- final compose ----------------
__global__ __launch_bounds__(128) void k_final(float* __restrict__ out,
                                               const float* __restrict__ rcW,
                                               const float* __restrict__ clf_b) {
  int t = blockIdx.x;  // b*N*N + i*N + j
  int b = t / (NN * NN);
  int ij = t % (NN * NN);
  int i = ij / NN, j = ij % NN;
  int c = threadIdx.x;
  if (c >= NC) return;
  size_t o = (size_t)t * NC + c;
  out[o] += rcW[((size_t)(b * NN) + i) * NC + c] +
            rcW[((size_t)(BB * NN) + (size_t)(b * NN) + j) * NC + c] + clf_b[c];
}

extern "C" void kernel_launch(void* const* d_in, const int* in_sizes, int n_in,
                              void* d_out, int out_size, void* d_ws, size_t ws_size,
                              hipStream_t stream) {
  const float* seq    = (const float*)d_in[0];
  const float* att    = (const float*)d_in[1];
  const int*   ep     = (const int*)d_in[2];
  const float* W_s    = (const float*)d_in[3];
  const float* W_o    = (const float*)d_in[4];
  const float* W_c    = (const float*)d_in[5];
  const float* A_bl   = (const float*)d_in[6];
  const float* b_bl   = (const float*)d_in[7];
  const float* W_attn = (const float*)d_in[8];
  const float* v_attn = (const float*)d_in[9];
  const float* clf_W  = (const float*)d_in[10];
  const float* clf_b  = (const float*)d_in[11];
  float* out = (float*)d_out;
  float* ws = (float*)d_ws;

  size_t off = 0;
  float* rep = ws + off; off += (size_t)BB * NN * HH;           // 98304
  float* rs  = ws + off; off += (size_t)BB * NN * WD;           // 98304
  float* ro  = ws + off; off += (size_t)BB * NN * WD;           // 98304
  float* ga  = ws + off; off += (size_t)BB * NN * NHEAD * SS;   // 1572864
  float* scg = ws + off; off += (size_t)BB * SS * WD;           // 3145728 (sc, then g)
  float* pa  = ws + off; off += (size_t)BB * NN * NN * SS;      // 4194304 (pa, then t)
  float* ctx = ws + off; off += (size_t)BB * NN * NN * WD;      // 3145728
  float* Mm  = ws + off; off += (size_t)BB * NN * NN * DD * DD; // 589824
  float* ebuf = ws + off; off += (size_t)BB * NN * NN;          // 4096
  float* arow = ws + off; off += (size_t)BB * NN * NN;          // 4096
  float* acol = ws + off; off += (size_t)BB * NN * NN;          // 4096
  float* rc   = ws + off; off += (size_t)2 * BB * NN * WD;      // 196608
  float* rcW  = ws + off; off += (size_t)2 * BB * NN * NC;      // 24832
  float* tbuf = pa;    // alias: pa dead after ctx GEMM
  float* gbuf = scg;   // alias: sc dead after ctx GEMM

  // 1. rep + ga gathers
  k_rep<<<dim3(BB * NN), dim3(256), 0, stream>>>(seq, ep, rep);
  k_ga<<<dim3(BB * NN * NHEAD), dim3(256), 0, stream>>>(att, ep, ga);

  // 2. rs = rep@W_s, ro = rep@W_o, sc = seq@W_c
  k_gemm<0><<<dim3(WD / 64, (BB * NN) / 64, 1), dim3(256), 0, stream>>>(
      rep, W_s, rs, BB * NN, WD, HH, 0LL, 0LL, 0LL, (const float*)nullptr, 0.f);
  k_gemm<0><<<dim3(WD / 64, (BB * NN) / 64, 1), dim3(256), 0, stream>>>(
      rep, W_o, ro, BB * NN, WD, HH, 0LL, 0LL, 0LL, (const float*)nullptr, 0.f);
  k_gemm<0><<<dim3(WD / 64, (BB * SS) / 64, 1), dim3(256), 0, stream>>>(
      seq, W_c, scg, BB * SS, WD, HH, 0LL, 0LL, 0LL, (const float*)nullptr, 0.f);

  // 3. pa (normalized)
  k_pa<<<dim3(BB * NN * NN), dim3(256), 0, stream>>>(ga, pa);

  // 4. ctx = pa @ sc  (batched per doc)
  k_gemm<0><<<dim3(WD / 64, (NN * NN) / 64, BB), dim3(256), 0, stream>>>(
      pa, scg, ctx, NN * NN, WD, SS, (long long)NN * NN * SS,
      (long long)SS * WD, (long long)NN * NN * WD, (const float*)nullptr, 0.f);

  // 5. M (Gram of Zs/Zo groups)
  k_M<<<dim3(BB * NN * NN), dim3(256), 0, stream>>>(ctx, rs, ro, Mm);

  // 6. g = M @ A_bl^T + 64*b_bl   (writes over sc region)
  k_gemm<1><<<dim3(WD / 64, (BB * NN * NN) / 64, 1), dim3(256), 0, stream>>>(
      Mm, A_bl, gbuf, BB * NN * NN, WD, DD * DD, 0LL, 0LL, 0LL, b_bl, (float)SPK);

  // 7. t = g @ W_attn  (writes over pa region)
  k_gemm<0><<<dim3(AD / 64, (BB * NN * NN) / 64, 1), dim3(256), 0, stream>>>(
      gbuf, W_attn, tbuf, BB * NN * NN, AD, WD, 0LL, 0LL, 0LL,
      (const float*)nullptr, 0.f);

  // 8. e = tanh(t) @ v_attn
  k_e<<<dim3(BB * NN * NN), dim3(AD), 0, stream>>>(tbuf, v_attn, ebuf);

  // 9. row/col softmax
  k_softmax<<<dim3(BB), dim3(NN * NN), 0, stream>>>(ebuf, arow, acol);

  // 10. rowctx/colctx
  k_rowcol<<<dim3(2 * BB * NN), dim3(256), 0, stream>>>(gbuf, arow, acol, rc);

  // 11. rcW = [rowctx;colctx] @ clf_W
  k_gemm<0><<<dim3((NC + 63) / 64, (2 * BB * NN) / 64, 1), dim3(256), 0, stream>>>(
      rc, clf_W, rcW, 2 * BB * NN, NC, WD, 0LL, 0LL, 0LL, (const float*)nullptr, 0.f);

  // 12. out = g @ clf_W
  k_gemm<0><<<dim3((NC + 63) / 64, (BB * NN * NN) / 64, 1), dim3(256), 0, stream>>>(
      gbuf, clf_W, out, BB * NN * NN, NC, WD, 0LL, 0LL, 0LL,
      (const float*)nullptr, 0.f);

  // 13. out += rcW_row[i] + rcW_col[j] + clf_b
  k_final<<<dim3(BB * NN * NN), dim3(128), 0, stream>>>(out, rcW, clf_b);
}

// Round 2
// 707.557 us; speedup vs baseline: 1.4632x; 1.4632x over previous
//
#include <hip/hip_runtime.h>
#include <hip/hip_bf16.h>
#include <math.h>

#define BB 4
#define SS 1024
#define HH 768
#define NHEAD 12
#define NN 32
#define MM 4
#define WD 768
#define AD 256
#define NC 97
#define SPK 64
#define DD 12
#define KP 160   // padded bilinear K (144 -> 160)

typedef __attribute__((ext_vector_type(8))) short short8;
typedef __attribute__((ext_vector_type(4))) float float4_t;

__device__ inline unsigned short f2bf(float x) {
  union { float f; unsigned int u; } v; v.f = x;
  unsigned int r = v.u + 0x7fffu + ((v.u >> 16) & 1u);
  return (unsigned short)(r >> 16);
}
__device__ inline float bf2f(unsigned short x) {
  union { unsigned int u; float f; } v; v.u = ((unsigned int)x) << 16;
  return v.f;
}

// ---------------- rep: logsumexp over mentions ----------------
__global__ void k_rep(const float* __restrict__ seq, const int* __restrict__ ep,
                      float* __restrict__ rep) {
  int bn = blockIdx.x; int b = bn / NN;
  const int* e = ep + (size_t)bn * MM;
  int i0 = e[0], i1 = e[1], i2 = e[2], i3 = e[3];
  const float* sb = seq + (size_t)b * SS * HH;
  for (int h = threadIdx.x; h < HH; h += blockDim.x) {
    float v0 = sb[(size_t)i0 * HH + h];
    float v1 = sb[(size_t)i1 * HH + h];
    float v2 = sb[(size_t)i2 * HH + h];
    float v3 = sb[(size_t)i3 * HH + h];
    float mx = fmaxf(fmaxf(v0, v1), fmaxf(v2, v3));
    float s = expf(v0 - mx) + expf(v1 - mx) + expf(v2 - mx) + expf(v3 - mx);
    rep[(size_t)bn * HH + h] = mx + logf(s);
  }
}

// ---------------- ga: sum of mention attention rows ----------------
__global__ void k_ga(const float* __restrict__ att, const int* __restrict__ ep,
                     float* __restrict__ ga) {
  int t = blockIdx.x;
  int h = t % NHEAD;
  int bn = t / NHEAD;
  int b = bn / NN;
  const int* e = ep + (size_t)bn * MM;
  int i0 = e[0], i1 = e[1], i2 = e[2], i3 = e[3];
  const float* ab = att + ((size_t)b * NHEAD + h) * SS * SS;
  float* go = ga + ((size_t)bn * NHEAD + h) * SS;
  for (int s = threadIdx.x; s < SS; s += blockDim.x) {
    go[s] = ab[(size_t)i0 * SS + s] + ab[(size_t)i1 * SS + s] +
            ab[(size_t)i2 * SS + s] + ab[(size_t)i3 * SS + s];
  }
}

// ---------------- pa: pairwise product over heads + normalize, bf16 out ----
__global__ __launch_bounds__(256) void k_pa(const float* __restrict__ ga,
                                            unsigned short* __restrict__ pa) {
  int t = blockIdx.x;               // b*N*N + i*N + j
  int j = t % NN;
  int i = (t / NN) % NN;
  int b = t / (NN * NN);
  const float* gi = ga + ((size_t)(b * NN + i)) * NHEAD * SS;
  const float* gj = ga + ((size_t)(b * NN + j)) * NHEAD * SS;
  float acc[4];
  float tot = 0.f;
#pragma unroll
  for (int r = 0; r < 4; ++r) {
    int s = threadIdx.x + r * 256;
    float a = 0.f;
#pragma unroll
    for (int h = 0; h < NHEAD; ++h) a += gi[h * SS + s] * gj[h * SS + s];
    acc[r] = a;
    tot += a;
  }
  __shared__ float red[256];
  red[threadIdx.x] = tot;
  __syncthreads();
  for (int o = 128; o > 0; o >>= 1) {
    if (threadIdx.x < o) red[threadIdx.x] += red[threadIdx.x + o];
    __syncthreads();
  }
  float inv = 1.0f / red[0];
  unsigned short* po = pa + (size_t)t * SS;
#pragma unroll
  for (int r = 0; r < 4; ++r) {
    int s = threadIdx.x + r * 256;
    po[s] = f2bf(acc[r] * inv);
  }
}

// ---------------- fp32 tiled GEMM (small matrices only) ----------------
template <int TRANS_B>
__global__ __launch_bounds__(256)
void k_gemm(const float* __restrict__ A, const float* __restrict__ B,
            float* __restrict__ C, int Mr, int Nc, int Kd,
            long long sA, long long sB, long long sC,
            const float* __restrict__ bias, float biasScale) {
  A += (long long)blockIdx.z * sA;
  B += (long long)blockIdx.z * sB;
  C += (long long)blockIdx.z * sC;
  __shared__ float As[16][65];
  __shared__ float Bs[16][65];
  const int tid = threadIdx.x;
  const int tm = tid >> 4;
  const int tn = tid & 15;
  const int m0 = blockIdx.y * 64;
  const int n0 = blockIdx.x * 64;
  float acc[4][4] = {};
  for (int k0 = 0; k0 < Kd; k0 += 16) {
    {
      const int ak = tid & 15;
      const int am = tid >> 4;
#pragma unroll
      for (int c = 0; c < 4; ++c) {
        As[ak][am + 16 * c] = A[(size_t)(m0 + am + 16 * c) * Kd + k0 + ak];
      }
    }
    if (TRANS_B) {
      const int bk = tid & 15;
      const int bn = tid >> 4;
#pragma unroll
      for (int c = 0; c < 4; ++c) {
        int n = n0 + bn + 16 * c;
        Bs[bk][bn + 16 * c] = (n < Nc) ? B[(size_t)n * Kd + k0 + bk] : 0.0f;
      }
    } else {
      const int bn = tid & 63;
      const int bk = tid >> 6;
#pragma unroll
      for (int c = 0; c < 4; ++c) {
        int n = n0 + bn;
        Bs[bk + 4 * c][bn] = (n < Nc) ? B[(size_t)(k0 + bk + 4 * c) * Nc + n] : 0.0f;
      }
    }
    __syncthreads();
#pragma unroll
    for (int k = 0; k < 16; ++k) {
      float a[4], bv[4];
#pragma unroll
      for (int i = 0; i < 4; ++i) a[i] = As[k][tm + 16 * i];
#pragma unroll
      for (int j = 0; j < 4; ++j) bv[j] = Bs[k][tn + 16 * j];
#pragma unroll
      for (int i = 0; i < 4; ++i)
#pragma unroll
        for (int j = 0; j < 4; ++j) acc[i][j] += a[i] * bv[j];
    }
    __syncthreads();
  }
#pragma unroll
  for (int i = 0; i < 4; ++i) {
    int m = m0 + tm + 16 * i;
#pragma unroll
    for (int j = 0; j < 4; ++j) {
      int n = n0 + tn + 16 * j;
      if (n < Nc) {
        float v = acc[i][j];
        if (bias) v += biasScale * bias[n];
        C[(size_t)m * Nc + n] = v;
      }
    }
  }
}

// ---------------- bf16 MFMA GEMM, NT layout ----------------
// C[m,n] = sum_k A[m,k]*B[n,k];  A:[M][K] bf16 (lda=K), B:[N][K] bf16 (ldb),
// C fp32 or bf16, ldc. M multiple of 128. B buffer rows must cover n0+127
// (pad with zeros); stores masked by n<Nc. 128x128 tile, 4 waves, 16x16x32.
#define LDSW 40
template <int C_BF16>
__global__ __launch_bounds__(256)
void k_mm(const unsigned short* __restrict__ A, const unsigned short* __restrict__ B,
          void* __restrict__ Cv, int Nc, int K, int ldb, int ldc,
          long long sA, long long sB, long long sC,
          const float* __restrict__ bias, float biasScale) {
  A += (long long)blockIdx.z * sA;
  B += (long long)blockIdx.z * sB;
  __shared__ __align__(16) unsigned short As[128 * LDSW];
  __shared__ __align__(16) unsigned short Bs[128 * LDSW];
  const int tid = threadIdx.x;
  const int m0 = blockIdx.y * 128;
  const int n0 = blockIdx.x * 128;
  const int lane = tid & 63;
  const int w = tid >> 6;
  const int wr = (w >> 1) * 64, wc = (w & 1) * 64;
  const int q = lane >> 4, l16 = lane & 15;
  float4_t acc[4][4] = {};
  const int sr = tid >> 2;          // 0..63
  const int scc = (tid & 3) * 8;    // 0,8,16,24
  const unsigned short* Ag = A + (size_t)(m0 + sr) * K + scc;
  const unsigned short* Bg = B + (size_t)(n0 + sr) * ldb + scc;
  for (int k0 = 0; k0 < K; k0 += 32) {
    *(short8*)&As[sr * LDSW + scc] = *(const short8*)&Ag[k0];
    *(short8*)&As[(sr + 64) * LDSW + scc] = *(const short8*)&Ag[(size_t)64 * K + k0];
    *(short8*)&Bs[sr * LDSW + scc] = *(const short8*)&Bg[k0];
    *(short8*)&Bs[(sr + 64) * LDSW + scc] = *(const short8*)&Bg[(size_t)64 * ldb + k0];
    __syncthreads();
    short8 af[4], bfr[4];
#pragma unroll
    for (int i = 0; i < 4; ++i)
      af[i] = *(const short8*)&As[(wr + i * 16 + l16) * LDSW + q * 8];
#pragma unroll
    for (int j = 0; j < 4; ++j)
      bfr[j] = *(const short8*)&Bs[(wc + j * 16 + l16) * LDSW + q * 8];
#pragma unroll
    for (int i = 0; i < 4; ++i)
#pragma unroll
      for (int j = 0; j < 4; ++j)
        acc[i][j] = __builtin_amdgcn_mfma_f32_16x16x32_bf16(af[i], bfr[j], acc[i][j], 0, 0, 0);
    __syncthreads();
  }
  float* Cf = (float*)Cv + (long long)blockIdx.z * sC;
  unsigned short* Cb = (unsigned short*)Cv + (long long)blockIdx.z * sC;
#pragma unroll
  for (int i = 0; i < 4; ++i) {
    int mbase = m0 + wr + i * 16 + q * 4;
#pragma unroll
    for (int j = 0; j < 4; ++j) {
      int n = n0 + wc + j * 16 + l16;
      if (n < Nc) {
        float badd = bias ? biasScale * bias[n] : 0.f;
#pragma unroll
        for (int r = 0; r < 4; ++r) {
          float v = acc[i][j][r] + badd;
          size_t off = (size_t)(mbase + r) * ldc + n;
          if (C_BF16) Cb[off] = f2bf(v);
          else        Cf[off] = v;
        }
      }
    }
  }
}

// ---------------- transpose fp32 [R][C] -> bf16 [Cp][R], zero-pad rows ----
__global__ __launch_bounds__(256)
void k_transpose_bf(const float* __restrict__ in, unsigned short* __restrict__ out,
                    int R, int C, int Cp) {
  __shared__ float tile[32][33];
  int r0 = blockIdx.x * 32, c0 = blockIdx.y * 32;
  int tx = threadIdx.x & 31, ty = threadIdx.x >> 5;  // 32x8
#pragma unroll
  for (int i = 0; i < 32; i += 8) {
    int r = r0 + ty + i, c = c0 + tx;
    tile[ty + i][tx] = (c < C) ? in[(size_t)r * C + c] : 0.f;
  }
  __syncthreads();
#pragma unroll
  for (int i = 0; i < 32; i += 8) {
    int c = c0 + ty + i, r = r0 + tx;
    if (c < Cp) out[(size_t)c * R + r] = f2bf(tile[tx][ty + i]);
  }
}

// ---------------- fp32 -> bf16 elementwise ----------------
__global__ void k_cvt(const float* __restrict__ in, unsigned short* __restrict__ out,
                      int n) {
  int i = (blockIdx.x * blockDim.x + threadIdx.x) * 4;
  if (i < n) {
    float4 v = *(const float4*)&in[i];
    out[i + 0] = f2bf(v.x); out[i + 1] = f2bf(v.y);
    out[i + 2] = f2bf(v.z); out[i + 3] = f2bf(v.w);
  }
}

// ---------------- A_bl [768][144] fp32 -> [768][160] bf16 padded ----------
__global__ void k_abl(const float* __restrict__ in, unsigned short* __restrict__ out) {
  int w = blockIdx.x;
  int pq = threadIdx.x;  // 0..159
  out[(size_t)w * KP + pq] = (pq < DD * DD) ? f2bf(in[(size_t)w * DD * DD + pq]) : 0;
}

// ---------------- Zs/Zo -> Gram matrix M (bf16, padded to 160) ------------
__global__ __launch_bounds__(256) void k_M(const float* __restrict__ ctx,
                                           const float* __restrict__ rs,
                                           const float* __restrict__ ro,
                                           unsigned short* __restrict__ Mm) {
  int t = blockIdx.x;  // b*N*N + i*N + j
  int b = t / (NN * NN);
  int ij = t % (NN * NN);
  int i = ij / NN;
  __shared__ float zs[WD];
  __shared__ float zo[WD];
  const float* cx = ctx + (size_t)t * WD;
  const float* rsi = rs + ((size_t)(b * NN + i)) * WD;
  const float* roi = ro + ((size_t)(b * NN + i)) * WD;
  for (int wd = threadIdx.x; wd < WD; wd += blockDim.x) {
    float c = cx[wd];
    zs[wd] = tanhf(rsi[wd] + c);
    zo[wd] = tanhf(roi[wd] + c);
  }
  __syncthreads();
  int pq = threadIdx.x;
  if (pq < KP) {
    float s = 0.f;
    if (pq < DD * DD) {
      int p = pq / DD, qq = pq % DD;
#pragma unroll
      for (int k = 0; k < SPK; ++k) s += zs[p * SPK + k] * zo[qq * SPK + k];
    }
    Mm[(size_t)t * KP + pq] = f2bf(s);
  }
}

// ---------------- e = tanh(t) @ v_attn ----------------
__global__ __launch_bounds__(AD) void k_e(const float* __restrict__ tbuf,
                                          const float* __restrict__ v_attn,
                                          float* __restrict__ e) {
  int r = blockIdx.x;
  int a = threadIdx.x;
  float v = tanhf(tbuf[(size_t)r * AD + a]) * v_attn[a];
  __shared__ float red[AD];
  red[a] = v;
  __syncthreads();
  for (int o = AD / 2; o > 0; o >>= 1) {
    if (a < o) red[a] += red[a + o];
    __syncthreads();
  }
  if (a == 0) e[r] = red[0];
}

// ---------------- row/col softmax over the 32x32 pair grid -----------------
__global__ __launch_bounds__(1024) void k_softmax(const float* __restrict__ e,
                                                  float* __restrict__ arow,
                                                  float* __restrict__ acol) {
  int b = blockIdx.x;
  __shared__ float E[NN][NN + 1];
  __shared__ float Rm[NN], Rs[NN];
  int tid = threadIdx.x;
  int i = tid / NN, j = tid % NN;
  E[i][j] = e[(size_t)b * NN * NN + tid];
  __syncthreads();
  if (tid < NN) {
    float mx = -1e30f;
    for (int jj = 0; jj < NN; ++jj) mx = fmaxf(mx, E[tid][jj]);
    float s = 0.f;
    for (int jj = 0; jj < NN; ++jj) s += expf(E[tid][jj] - mx);
    Rm[tid] = mx;
    Rs[tid] = s;
  }
  __syncthreads();
  arow[(size_t)b * NN * NN + tid] = expf(E[i][j] - Rm[i]) / Rs[i];
  __syncthreads();
  if (tid < NN) {
    float mx = -1e30f;
    for (int ii = 0; ii < NN; ++ii) mx = fmaxf(mx, E[ii][tid]);
    float s = 0.f;
    for (int ii = 0; ii < NN; ++ii) s += expf(E[ii][tid] - mx);
    Rm[tid] = mx;
    Rs[tid] = s;
  }
  __syncthreads();
  acol[(size_t)b * NN * NN + tid] = expf(E[i][j] - Rm[j]) / Rs[j];
}

// ---------------- rowctx / colctx (g is bf16) ----------------
__global__ __launch_bounds__(256) void k_rowcol(const unsigned short* __restrict__ g,
                                                const float* __restrict__ arow,
                                                const float* __restrict__ acol,
                                                float* __restrict__ rc) {
  int t = blockIdx.x;              // [0, 2*B*N)
  int which = t / (BB * NN);       // 0 = row, 1 = col
  int bn = t % (BB * NN);
  int b = bn / NN, x = bn % NN;
  const unsigned short* gb = g + (size_t)b * NN * NN * WD;
  float* out = rc + ((size_t)which * BB * NN + bn) * WD;
  for (int o = threadIdx.x; o < WD; o += blockDim.x) {
    float s = 0.f;
    if (which == 0) {
      const float* ar = arow + (size_t)b * NN * NN + (size_t)x * NN;
#pragma unroll 4
      for (int jj = 0; jj < NN; ++jj)
        s += ar[jj] * bf2f(gb[((size_t)x * NN + jj) * WD + o]);
    } else {
      const float* ac = acol + (size_t)b * NN * NN;
#pragma unroll 4
      for (int ii = 0; ii < NN; ++ii)
        s += ac[(size_t)ii * NN + x] * bf2f(gb[((size_t)ii * NN + x) * WD + o]);
    }
    out[o] = s;
  }
}

// ---------------- final compose ----------------
__global__ __launch_bounds__(128) void k_final(float* __restrict__ out,
                                               const float* __restrict__ rcW,
                                               const float* __restrict__ clf_b) {
  int t = blockIdx.x;  // b*N*N + i*N + j
  int b = t / (NN * NN);
  int ij = t % (NN * NN);
  int i = ij / NN, j = ij % NN;
  int c = threadIdx.x;
  if (c >= NC) return;
  size_t o = (size_t)t * NC + c;
  out[o] += rcW[((size_t)(b * NN) + i) * NC + c] +
            rcW[((size_t)(BB * NN) + (size_t)(b * NN) + j) * NC + c] + clf_b[c];
}

extern "C" void kernel_launch(void* const* d_in, const int* in_sizes, int n_in,
                              void* d_out, int out_size, void* d_ws, size_t ws_size,
                              hipStream_t stream) {
  const float* seq    = (const float*)d_in[0];
  const float* att    = (const float*)d_in[1];
  const int*   ep     = (const int*)d_in[2];
  const float* W_s    = (const float*)d_in[3];
  const float* W_o    = (const float*)d_in[4];
  const float* W_c    = (const float*)d_in[5];
  const float* A_bl   = (const float*)d_in[6];
  const float* b_bl   = (const float*)d_in[7];
  const float* W_attn = (const float*)d_in[8];
  const float* v_attn = (const float*)d_in[9];
  const float* clf_W  = (const float*)d_in[10];
  const float* clf_b  = (const float*)d_in[11];
  float* out = (float*)d_out;

  char* base = (char*)d_ws;
  size_t off = 0;
  auto alloc = [&](size_t bytes) {
    char* p = base + off;
    off += (bytes + 255) & ~(size_t)255;
    return p;
  };
  float* rep  = (float*)alloc((size_t)BB * NN * HH * 4);
  float* rs   = (float*)alloc((size_t)BB * NN * WD * 4);
  float* ro   = (float*)alloc((size_t)BB * NN * WD * 4);
  float* ga   = (float*)alloc((size_t)BB * NN * NHEAD * SS * 4);        // reused: t fp32
  unsigned short* paB  = (unsigned short*)alloc((size_t)BB * NN * NN * SS * 2);  // reused: g bf16
  unsigned short* seqB = (unsigned short*)alloc((size_t)BB * SS * HH * 2);
  unsigned short* WcT  = (unsigned short*)alloc((size_t)HH * WD * 2);
  unsigned short* scT  = (unsigned short*)alloc((size_t)WD * BB * SS * 2);
  float* ctx  = (float*)alloc((size_t)BB * NN * NN * WD * 4);
  unsigned short* MmB  = (unsigned short*)alloc((size_t)BB * NN * NN * KP * 2);
  unsigned short* AblB = (unsigned short*)alloc((size_t)WD * KP * 2);
  unsigned short* WaT  = (unsigned short*)alloc((size_t)AD * WD * 2);
  unsigned short* clfT = (unsigned short*)alloc((size_t)128 * WD * 2);
  float* ebuf = (float*)alloc((size_t)BB * NN * NN * 4);
  float* arow = (float*)alloc((size_t)BB * NN * NN * 4);
  float* acol = (float*)alloc((size_t)BB * NN * NN * 4);
  float* rc   = (float*)alloc((size_t)2 * BB * NN * WD * 4);
  float* rcW  = (float*)alloc((size_t)2 * BB * NN * NC * 4);
  float* tbuf = ga;                       // alias: ga dead after k_pa
  unsigned short* gB = paB;               // alias: pa dead after ctx GEMM

  // 0. conversions / transposes (cheap, once per launch)
  k_cvt<<<dim3((BB * SS * HH / 4 + 255) / 256), dim3(256), 0, stream>>>(
      seq, seqB, BB * SS * HH);
  k_transpose_bf<<<dim3(HH / 32, WD / 32), dim3(256), 0, stream>>>(W_c, WcT, HH, WD, WD);
  k_transpose_bf<<<dim3(WD / 32, AD / 32), dim3(256), 0, stream>>>(W_attn, WaT, WD, AD, AD);
  k_transpose_bf<<<dim3(WD / 32, 128 / 32), dim3(256), 0, stream>>>(clf_W, clfT, WD, NC, 128);
  k_abl<<<dim3(WD), dim3(KP), 0, stream>>>(A_bl, AblB);

  // 1. rep + ga gathers
  k_rep<<<dim3(BB * NN), dim3(256), 0, stream>>>(seq, ep, rep);
  k_ga<<<dim3(BB * NN * NHEAD), dim3(256), 0, stream>>>(att, ep, ga);

  // 2. rs = rep@W_s, ro = rep@W_o (small, fp32 path)
  k_gemm<0><<<dim3(WD / 64, (BB * NN) / 64, 1), dim3(256), 0, stream>>>(
      rep, W_s, rs, BB * NN, WD, HH, 0LL, 0LL, 0LL, (const float*)nullptr, 0.f);
  k_gemm<0><<<dim3(WD / 64, (BB * NN) / 64, 1), dim3(256), 0, stream>>>(
      rep, W_o, ro, BB * NN, WD, HH, 0LL, 0LL, 0LL, (const float*)nullptr, 0.f);

  // 3. scT[w][b*S+s] = (seq@W_c)^T : A=WcT [768][768], B=seqB [4096][768]
  k_mm<1><<<dim3(BB * SS / 128, WD / 128, 1), dim3(256), 0, stream>>>(
      WcT, seqB, scT, BB * SS, HH, HH, BB * SS, 0LL, 0LL, 0LL,
      (const float*)nullptr, 0.f);

  // 4. pa (normalized, bf16)
  k_pa<<<dim3(BB * NN * NN), dim3(256), 0, stream>>>(ga, paB);

  // 5. ctx = pa @ sc  : A=paB [1024][1024]/b, B=scT+b*1024 (ldb=4096)
  k_mm<0><<<dim3(WD / 128, NN * NN / 128, BB), dim3(256), 0, stream>>>(
      paB, scT, ctx, WD, SS, BB * SS, WD,
      (long long)NN * NN * SS, (long long)SS, (long long)NN * NN * WD,
      (const float*)nullptr, 0.f);

  // 6. M (Gram of Zs/Zo groups), bf16 padded [4096][160]
  k_M<<<dim3(BB * NN * NN), dim3(256), 0, stream>>>(ctx, rs, ro, MmB);

  // 7. g = M @ A_bl^T + 64*b_bl : A=MmB [4096][160], B=AblB [768][160], bf16 out
  k_mm<1><<<dim3(WD / 128, BB * NN * NN / 128, 1), dim3(256), 0, stream>>>(
      MmB, AblB, gB, WD, KP, KP, WD, 0LL, 0LL, 0LL, b_bl, (float)SPK);

  // 8. t = g @ W_attn : A=gB, B=WaT [256][768], fp32 out
  k_mm<0><<<dim3(AD / 128, BB * NN * NN / 128, 1), dim3(256), 0, stream>>>(
      gB, WaT, tbuf, AD, WD, WD, AD, 0LL, 0LL, 0LL, (const float*)nullptr, 0.f);

  // 9. e = tanh(t) @ v_attn
  k_e<<<dim3(BB * NN * NN), dim3(AD), 0, stream>>>(tbuf, v_attn, ebuf);

  // 10. row/col softmax
  k_softmax<<<dim3(BB), dim3(NN * NN), 0, stream>>>(ebuf, arow, acol);

  // 11. rowctx/colctx from bf16 g
  k_rowcol<<<dim3(2 * BB * NN), dim3(256), 0, stream>>>(gB, arow, acol, rc);

  // 12. rcW = [rowctx;colctx] @ clf_W (small, fp32 path)
  k_gemm<0><<<dim3((NC + 63) / 64, (2 * BB * NN) / 64, 1), dim3(256), 0, stream>>>(
      rc, clf_W, rcW, 2 * BB * NN, NC, WD, 0LL, 0LL, 0LL, (const float*)nullptr, 0.f);

  // 13. out = g @ clf_W : A=gB, B=clfT [128][768] (rows 97..127 zero), Nc=97
  k_mm<0><<<dim3(1, BB * NN * NN / 128, 1), dim3(256), 0, stream>>>(
      gB, clfT, out, NC, WD, WD, NC, 0LL, 0LL, 0LL, (const float*)nullptr, 0.f);

  // 14. out += rcW_row[i] + rcW_col[j] + clf_b
  k_final<<<dim3(BB * NN * NN), dim3(128), 0, stream>>>(out, rcW, clf_b);
}

// Round 3
// 468.665 us; speedup vs baseline: 2.2090x; 1.5097x over previous
//
#include <hip/hip_runtime.h>
#include <hip/hip_bf16.h>
#include <math.h>

#define BB 4
#define SS 1024
#define HH 768
#define NHEAD 12
#define NN 32
#define MM 4
#define WD 768
#define AD 256
#define NC 97
#define SPK 64
#define DD 12
#define KP 160   // padded bilinear K (144 -> 160)

typedef __attribute__((ext_vector_type(8))) short short8;
typedef __attribute__((ext_vector_type(4))) float float4_t;

__device__ inline unsigned short f2bf(float x) {
  union { float f; unsigned int u; } v; v.f = x;
  unsigned int r = v.u + 0x7fffu + ((v.u >> 16) & 1u);
  return (unsigned short)(r >> 16);
}
__device__ inline float bf2f(unsigned short x) {
  union { unsigned int u; float f; } v; v.u = ((unsigned int)x) << 16;
  return v.f;
}

// async global->LDS, 16B per lane; LDS dest = wave-uniform base + lane*16
__device__ __forceinline__ void gl_lds16(unsigned short* l, const unsigned short* g) {
  __builtin_amdgcn_global_load_lds(
      (const __attribute__((address_space(1))) unsigned int*)g,
      (__attribute__((address_space(3))) unsigned int*)l, 16, 0, 0);
}

// ---------------- prep: all weight transposes + seq cvt + A_bl pad ---------
__device__ __forceinline__ void transpose_tile(const float* __restrict__ in,
                                               unsigned short* __restrict__ out,
                                               int R, int C, int Cp, int t, int tilesR) {
  __shared__ float tile[32][33];
  int r0 = (t % tilesR) * 32, c0 = (t / tilesR) * 32;
  int tx = threadIdx.x & 31, ty = threadIdx.x >> 5;  // 32x8
#pragma unroll
  for (int i = 0; i < 32; i += 8) {
    int r = r0 + ty + i, c = c0 + tx;
    tile[ty + i][tx] = (c < C) ? in[(size_t)r * C + c] : 0.f;
  }
  __syncthreads();
#pragma unroll
  for (int i = 0; i < 32; i += 8) {
    int c = c0 + ty + i, r = r0 + tx;
    if (c < Cp) out[(size_t)c * R + r] = f2bf(tile[tx][ty + i]);
  }
}

__global__ __launch_bounds__(256) void k_prep(
    const float* __restrict__ seq, const float* __restrict__ W_c,
    const float* __restrict__ W_attn, const float* __restrict__ clf_W,
    const float* __restrict__ W_s, const float* __restrict__ W_o,
    const float* __restrict__ A_bl,
    unsigned short* __restrict__ seqB, unsigned short* __restrict__ WcT,
    unsigned short* __restrict__ WaT, unsigned short* __restrict__ clfT,
    unsigned short* __restrict__ WsoT, unsigned short* __restrict__ AblB) {
  int bid = blockIdx.x;
  if (bid < 3072) {  // seq fp32 -> bf16 (4 elems/thread)
    int i = (bid * 256 + threadIdx.x) * 4;
    float4 v = *(const float4*)&seq[i];
    seqB[i + 0] = f2bf(v.x); seqB[i + 1] = f2bf(v.y);
    seqB[i + 2] = f2bf(v.z); seqB[i + 3] = f2bf(v.w);
    return;
  }
  bid -= 3072;
  if (bid < 576) { transpose_tile(W_c, WcT, HH, WD, WD, bid, 24); return; }
  bid -= 576;
  if (bid < 192) { transpose_tile(W_attn, WaT, WD, AD, AD, bid, 24); return; }
  bid -= 192;
  if (bid < 96)  { transpose_tile(clf_W, clfT, WD, NC, 128, bid, 24); return; }
  bid -= 96;
  if (bid < 576) { transpose_tile(W_s, WsoT, HH, WD, WD, bid, 24); return; }
  bid -= 576;
  if (bid < 576) { transpose_tile(W_o, WsoT + (size_t)WD * HH, HH, WD, WD, bid, 24); return; }
  bid -= 576;
  {  // A_bl [768][144] -> [768][160] bf16 zero-padded
    int idx = bid * 256 + threadIdx.x;
    int w = idx / KP, pq = idx % KP;
    if (w < WD) AblB[idx] = (pq < DD * DD) ? f2bf(A_bl[(size_t)w * DD * DD + pq]) : 0;
  }
}

// ---------------- rep: logsumexp over mentions (bf16 out) ----------------
__global__ void k_rep(const float* __restrict__ seq, const int* __restrict__ ep,
                      unsigned short* __restrict__ repB) {
  int bn = blockIdx.x; int b = bn / NN;
  const int* e = ep + (size_t)bn * MM;
  int i0 = e[0], i1 = e[1], i2 = e[2], i3 = e[3];
  const float* sb = seq + (size_t)b * SS * HH;
  for (int h = threadIdx.x; h < HH; h += blockDim.x) {
    float v0 = sb[(size_t)i0 * HH + h];
    float v1 = sb[(size_t)i1 * HH + h];
    float v2 = sb[(size_t)i2 * HH + h];
    float v3 = sb[(size_t)i3 * HH + h];
    float mx = fmaxf(fmaxf(v0, v1), fmaxf(v2, v3));
    float s = expf(v0 - mx) + expf(v1 - mx) + expf(v2 - mx) + expf(v3 - mx);
    repB[(size_t)bn * HH + h] = f2bf(mx + logf(s));
  }
}

// ---------------- ga: sum of mention attention rows ----------------
__global__ void k_ga(const float* __restrict__ att, const int* __restrict__ ep,
                     float* __restrict__ ga) {
  int t = blockIdx.x;
  int h = t % NHEAD;
  int bn = t / NHEAD;
  int b = bn / NN;
  const int* e = ep + (size_t)bn * MM;
  int i0 = e[0], i1 = e[1], i2 = e[2], i3 = e[3];
  const float* ab = att + ((size_t)b * NHEAD + h) * SS * SS;
  float* go = ga + ((size_t)bn * NHEAD + h) * SS;
  for (int s = threadIdx.x; s < SS; s += blockDim.x) {
    go[s] = ab[(size_t)i0 * SS + s] + ab[(size_t)i1 * SS + s] +
            ab[(size_t)i2 * SS + s] + ab[(size_t)i3 * SS + s];
  }
}

// ---------------- pa: pairwise product over heads + normalize, bf16 out ----
__global__ __launch_bounds__(256) void k_pa(const float* __restrict__ ga,
                                            unsigned short* __restrict__ pa) {
  int t = blockIdx.x;               // b*N*N + i*N + j
  int j = t % NN;
  int i = (t / NN) % NN;
  int b = t / (NN * NN);
  const float* gi = ga + ((size_t)(b * NN + i)) * NHEAD * SS;
  const float* gj = ga + ((size_t)(b * NN + j)) * NHEAD * SS;
  float acc[4];
  float tot = 0.f;
#pragma unroll
  for (int r = 0; r < 4; ++r) {
    int s = threadIdx.x + r * 256;
    float a = 0.f;
#pragma unroll
    for (int h = 0; h < NHEAD; ++h) a += gi[h * SS + s] * gj[h * SS + s];
    acc[r] = a;
    tot += a;
  }
  __shared__ float red[256];
  red[threadIdx.x] = tot;
  __syncthreads();
  for (int o = 128; o > 0; o >>= 1) {
    if (threadIdx.x < o) red[threadIdx.x] += red[threadIdx.x + o];
    __syncthreads();
  }
  float inv = 1.0f / red[0];
  unsigned short* po = pa + (size_t)t * SS;
#pragma unroll
  for (int r = 0; r < 4; ++r) {
    int s = threadIdx.x + r * 256;
    po[s] = f2bf(acc[r] * inv);
  }
}

// ---------------- bf16 MFMA GEMM, NT layout, async LDS staging -------------
// C[m,n] = sum_k A[m,k]*B[n,k];  A:[M][K] bf16, B:[N][K] bf16 (row stride ldb)
// MODE: 0 = fp32 C[m*ldc+n]; 1 = bf16 C[m*ldc+n]; 2 = fp32 C[n*ldc+m];
//       3 = fp32 C[m*ldc+n] + rcW[row(m)] + rcW[col(m)] + clf_b  (final fuse)
// M multiple of 128; B rows must cover n0+127 (zero-pad); K multiple of 32.
template <int MODE>
__global__ __launch_bounds__(256)
void k_mm(const unsigned short* __restrict__ A, const unsigned short* __restrict__ B,
          void* __restrict__ Cv, int Nc, int K, int ldb, int ldc,
          long long sA, long long sB, long long sC,
          const float* __restrict__ bias, float biasScale,
          const float* __restrict__ rcWp, const float* __restrict__ clf_b) {
  A += (long long)blockIdx.z * sA;
  B += (long long)blockIdx.z * sB;
  __shared__ __align__(16) unsigned short As[128 * 32];
  __shared__ __align__(16) unsigned short Bs[128 * 32];
  const int tid = threadIdx.x;
  const int m0 = blockIdx.y * 128;
  const int n0 = blockIdx.x * 128;
  const int lane = tid & 63;
  const int w = tid >> 6;
  const int wr = (w >> 1) * 64, wc = (w & 1) * 64;
  const int q = lane >> 4, l16 = lane & 15;
  const int lr = lane >> 2, lq = lane & 3;  // staging: row-in-16, 16B chunk
  float4_t acc[4][4] = {};
  const unsigned short* Ag0 = A + (size_t)(m0 + w * 16 + lr) * K + lq * 8;
  const unsigned short* Ag1 = Ag0 + (size_t)64 * K;
  const unsigned short* Bg0 = B + (size_t)(n0 + w * 16 + lr) * ldb + lq * 8;
  const unsigned short* Bg1 = Bg0 + (size_t)64 * ldb;
  unsigned short* Al0 = &As[(w * 16) * 32];
  unsigned short* Al1 = &As[(64 + w * 16) * 32];
  unsigned short* Bl0 = &Bs[(w * 16) * 32];
  unsigned short* Bl1 = &Bs[(64 + w * 16) * 32];
  for (int k0 = 0; k0 < K; k0 += 32) {
    gl_lds16(Al0, Ag0 + k0);
    gl_lds16(Al1, Ag1 + k0);
    gl_lds16(Bl0, Bg0 + k0);
    gl_lds16(Bl1, Bg1 + k0);
    __syncthreads();
    short8 af[4], bfr[4];
#pragma unroll
    for (int i = 0; i < 4; ++i)
      af[i] = *(const short8*)&As[(wr + i * 16 + l16) * 32 + q * 8];
#pragma unroll
    for (int j = 0; j < 4; ++j)
      bfr[j] = *(const short8*)&Bs[(wc + j * 16 + l16) * 32 + q * 8];
#pragma unroll
    for (int i = 0; i < 4; ++i)
#pragma unroll
      for (int j = 0; j < 4; ++j)
        acc[i][j] = __builtin_amdgcn_mfma_f32_16x16x32_bf16(af[i], bfr[j], acc[i][j], 0, 0, 0);
    __syncthreads();
  }
  float* Cf = (float*)Cv + (long long)blockIdx.z * sC;
  unsigned short* Cb = (unsigned short*)Cv + (long long)blockIdx.z * sC;
#pragma unroll
  for (int i = 0; i < 4; ++i) {
    int mbase = m0 + wr + i * 16 + q * 4;
#pragma unroll
    for (int j = 0; j < 4; ++j) {
      int n = n0 + wc + j * 16 + l16;
      if (n < Nc) {
        float badd = bias ? biasScale * bias[n] : 0.f;
#pragma unroll
        for (int r = 0; r < 4; ++r) {
          int m = mbase + r;
          float v = acc[i][j][r] + badd;
          if (MODE == 3) {
            int b = m >> 10, ii = (m >> 5) & 31, jj = m & 31;
            v += rcWp[(size_t)(b * NN + ii) * NC + n] +
                 rcWp[(size_t)(BB * NN + b * NN + jj) * NC + n] + clf_b[n];
          }
          if (MODE == 1)      Cb[(size_t)m * ldc + n] = f2bf(v);
          else if (MODE == 2) Cf[(size_t)n * ldc + m] = v;
          else                Cf[(size_t)m * ldc + n] = v;
        }
      }
    }
  }
}

// ---------------- Zs/Zo -> Gram matrix M (bf16, padded to 160) ------------
// rso: [128][1536] fp32, cols 0..767 = rep@W_s, 768..1535 = rep@W_o
__global__ __launch_bounds__(256) void k_M(const unsigned short* __restrict__ ctx,
                                           const float* __restrict__ rso,
                                           unsigned short* __restrict__ Mm) {
  int t = blockIdx.x;  // b*N*N + i*N + j
  const float* rsi = rso + (size_t)(t >> 5) * 1536;
  __shared__ float zsT[64 * 13];  // [k][p], padded to 13 -> conflict-free Gram
  __shared__ float zoT[64 * 13];
  const unsigned short* cx = ctx + (size_t)t * WD;
  for (int wd = threadIdx.x; wd < WD; wd += blockDim.x) {
    float c = bf2f(cx[wd]);
    int k = wd & 63, p = wd >> 6;
    zsT[k * 13 + p] = tanhf(rsi[wd] + c);
    zoT[k * 13 + p] = tanhf(rsi[WD + wd] + c);
  }
  __syncthreads();
  int pq = threadIdx.x;
  if (pq < KP) {
    float s = 0.f;
    if (pq < DD * DD) {
      int p = pq / DD, qq = pq % DD;
#pragma unroll
      for (int k = 0; k < SPK; ++k) s += zsT[k * 13 + p] * zoT[k * 13 + qq];
    }
    Mm[(size_t)t * KP + pq] = f2bf(s);
  }
}

// ---------------- e = tanh(t) @ v_attn ----------------
__global__ __launch_bounds__(AD) void k_e(const float* __restrict__ tbuf,
                                          const float* __restrict__ v_attn,
                                          float* __restrict__ e) {
  int r = blockIdx.x;
  int a = threadIdx.x;
  float v = tanhf(tbuf[(size_t)r * AD + a]) * v_attn[a];
  __shared__ float red[AD];
  red[a] = v;
  __syncthreads();
  for (int o = AD / 2; o > 0; o >>= 1) {
    if (a < o) red[a] += red[a + o];
    __syncthreads();
  }
  if (a == 0) e[r] = red[0];
}

// ---------------- row/col softmax over the 32x32 pair grid -----------------
__global__ __launch_bounds__(1024) void k_softmax(const float* __restrict__ e,
                                                  float* __restrict__ arow,
                                                  float* __restrict__ acol) {
  int b = blockIdx.x;
  __shared__ float E[NN][NN + 1];
  __shared__ float Rm[NN], Rs[NN];
  int tid = threadIdx.x;
  int i = tid / NN, j = tid % NN;
  E[i][j] = e[(size_t)b * NN * NN + tid];
  __syncthreads();
  if (tid < NN) {
    float mx = -1e30f;
    for (int jj = 0; jj < NN; ++jj) mx = fmaxf(mx, E[tid][jj]);
    float s = 0.f;
    for (int jj = 0; jj < NN; ++jj) s += expf(E[tid][jj] - mx);
    Rm[tid] = mx;
    Rs[tid] = s;
  }
  __syncthreads();
  arow[(size_t)b * NN * NN + tid] = expf(E[i][j] - Rm[i]) / Rs[i];
  __syncthreads();
  if (tid < NN) {
    float mx = -1e30f;
    for (int ii = 0; ii < NN; ++ii) mx = fmaxf(mx, E[ii][tid]);
    float s = 0.f;
    for (int ii = 0; ii < NN; ++ii) s += expf(E[ii][tid] - mx);
    Rm[tid] = mx;
    Rs[tid] = s;
  }
  __syncthreads();
  acol[(size_t)b * NN * NN + tid] = expf(E[i][j] - Rm[j]) / Rs[j];
}

// ---------------- rowctx / colctx (g bf16 in, bf16 out) ----------------
__global__ __launch_bounds__(256) void k_rowcol(const unsigned short* __restrict__ g,
                                                const float* __restrict__ arow,
                                                const float* __restrict__ acol,
                                                unsigned short* __restrict__ rc) {
  int t = blockIdx.x;              // [0, 2*B*N)
  int which = t / (BB * NN);       // 0 = row, 1 = col
  int bn = t % (BB * NN);
  int b = bn / NN, x = bn % NN;
  const unsigned short* gb = g + (size_t)b * NN * NN * WD;
  unsigned short* out = rc + ((size_t)which * BB * NN + bn) * WD;
  for (int o = threadIdx.x; o < WD; o += blockDim.x) {
    float s = 0.f;
    if (which == 0) {
      const float* ar = arow + (size_t)b * NN * NN + (size_t)x * NN;
#pragma unroll 4
      for (int jj = 0; jj < NN; ++jj)
        s += ar[jj] * bf2f(gb[((size_t)x * NN + jj) * WD + o]);
    } else {
      const float* ac = acol + (size_t)b * NN * NN;
#pragma unroll 4
      for (int ii = 0; ii < NN; ++ii)
        s += ac[(size_t)ii * NN + x] * bf2f(gb[((size_t)ii * NN + x) * WD + o]);
    }
    out[o] = f2bf(s);
  }
}

extern "C" void kernel_launch(void* const* d_in, const int* in_sizes, int n_in,
                              void* d_out, int out_size, void* d_ws, size_t ws_size,
                              hipStream_t stream) {
  const float* seq    = (const float*)d_in[0];
  const float* att    = (const float*)d_in[1];
  const int*   ep     = (const int*)d_in[2];
  const float* W_s    = (const float*)d_in[3];
  const float* W_o    = (const float*)d_in[4];
  const float* W_c    = (const float*)d_in[5];
  const float* A_bl   = (const float*)d_in[6];
  const float* b_bl   = (const float*)d_in[7];
  const float* W_attn = (const float*)d_in[8];
  const float* v_attn = (const float*)d_in[9];
  const float* clf_W  = (const float*)d_in[10];
  const float* clf_b  = (const float*)d_in[11];
  float* out = (float*)d_out;

  char* base = (char*)d_ws;
  size_t off = 0;
  auto alloc = [&](size_t bytes) {
    char* p = base + off;
    off += (bytes + 255) & ~(size_t)255;
    return p;
  };
  unsigned short* repB = (unsigned short*)alloc((size_t)BB * NN * HH * 2);
  float* rso  = (float*)alloc((size_t)BB * NN * 2 * WD * 4);              // [128][1536]
  float* ga   = (float*)alloc((size_t)BB * NN * NHEAD * SS * 4);          // reused: t fp32
  unsigned short* paB  = (unsigned short*)alloc((size_t)BB * NN * NN * SS * 2);  // reused: g bf16
  unsigned short* seqB = (unsigned short*)alloc((size_t)BB * SS * HH * 2);
  unsigned short* WcT  = (unsigned short*)alloc((size_t)HH * WD * 2);
  unsigned short* WaT  = (unsigned short*)alloc((size_t)AD * WD * 2);
  unsigned short* clfT = (unsigned short*)alloc((size_t)128 * WD * 2);
  unsigned short* WsoT = (unsigned short*)alloc((size_t)2 * WD * HH * 2); // [1536][768]
  unsigned short* scT  = (unsigned short*)alloc((size_t)WD * BB * SS * 2);
  unsigned short* ctxB = (unsigned short*)alloc((size_t)BB * NN * NN * WD * 2);
  unsigned short* MmB  = (unsigned short*)alloc((size_t)BB * NN * NN * KP * 2);
  unsigned short* AblB = (unsigned short*)alloc((size_t)WD * KP * 2);
  float* ebuf = (float*)alloc((size_t)BB * NN * NN * 4);
  float* arow = (float*)alloc((size_t)BB * NN * NN * 4);
  float* acol = (float*)alloc((size_t)BB * NN * NN * 4);
  unsigned short* rcB = (unsigned short*)alloc((size_t)2 * BB * NN * WD * 2);
  float* rcW  = (float*)alloc((size_t)2 * BB * NN * NC * 4);
  float* tbuf = ga;                       // alias: ga dead after k_pa
  unsigned short* gB = paB;               // alias: pa dead after ctx GEMM

  const float* nof = nullptr;

  // 1. prep: seq->bf16, W_c/W_attn/clf_W/W_s/W_o transposes, A_bl pad
  k_prep<<<dim3(5568), dim3(256), 0, stream>>>(seq, W_c, W_attn, clf_W, W_s, W_o,
                                               A_bl, seqB, WcT, WaT, clfT, WsoT, AblB);

  // 2. gathers
  k_rep<<<dim3(BB * NN), dim3(256), 0, stream>>>(seq, ep, repB);
  k_ga<<<dim3(BB * NN * NHEAD), dim3(256), 0, stream>>>(att, ep, ga);

  // 3. rso[bn][{W_s|W_o}] = (rep @ [W_s|W_o]) : A=WsoT [1536][768], B=repB, C transposed
  k_mm<2><<<dim3(1, 12, 1), dim3(256), 0, stream>>>(
      WsoT, repB, rso, BB * NN, HH, HH, 2 * WD, 0LL, 0LL, 0LL, nof, 0.f, nof, nof);

  // 4. scT[w][b*S+s] = (seq@W_c)^T : A=WcT [768][768], B=seqB [4096][768]
  k_mm<1><<<dim3(BB * SS / 128, WD / 128, 1), dim3(256), 0, stream>>>(
      WcT, seqB, scT, BB * SS, HH, HH, BB * SS, 0LL, 0LL, 0LL, nof, 0.f, nof, nof);

  // 5. pa (normalized, bf16)
  k_pa<<<dim3(BB * NN * NN), dim3(256), 0, stream>>>(ga, paB);

  // 6. ctx = pa @ sc (bf16 out): A=paB [1024][1024]/b, B=scT+b*1024 (ldb=4096)
  k_mm<1><<<dim3(WD / 128, NN * NN / 128, BB), dim3(256), 0, stream>>>(
      paB, scT, ctxB, WD, SS, BB * SS, WD,
      (long long)NN * NN * SS, (long long)SS, (long long)NN * NN * WD,
      nof, 0.f, nof, nof);

  // 7. M (Gram of Zs/Zo groups), bf16 padded [4096][160]
  k_M<<<dim3(BB * NN * NN), dim3(256), 0, stream>>>(ctxB, rso, MmB);

  // 8. g = M @ A_bl^T + 64*b_bl (bf16 out)
  k_mm<1><<<dim3(WD / 128, BB * NN * NN / 128, 1), dim3(256), 0, stream>>>(
      MmB, AblB, gB, WD, KP, KP, WD, 0LL, 0LL, 0LL, b_bl, (float)SPK, nof, nof);

  // 9. t = g @ W_attn (fp32 out)
  k_mm<0><<<dim3(AD / 128, BB * NN * NN / 128, 1), dim3(256), 0, stream>>>(
      gB, WaT, tbuf, AD, WD, WD, AD, 0LL, 0LL, 0LL, nof, 0.f, nof, nof);

  // 10. e = tanh(t) @ v_attn
  k_e<<<dim3(BB * NN * NN), dim3(AD), 0, stream>>>(tbuf, v_attn, ebuf);

  // 11. row/col softmax
  k_softmax<<<dim3(BB), dim3(NN * NN), 0, stream>>>(ebuf, arow, acol);

  // 12. rowctx/colctx (bf16 out)
  k_rowcol<<<dim3(2 * BB * NN), dim3(256), 0, stream>>>(gB, arow, acol, rcB);

  // 13. rcW = [rowctx;colctx] @ clf_W
  k_mm<0><<<dim3(1, 2, 1), dim3(256), 0, stream>>>(
      rcB, clfT, rcW, NC, WD, WD, NC, 0LL, 0LL, 0LL, nof, 0.f, nof, nof);

  // 14. out = g @ clf_W + rcW_row[i] + rcW_col[j] + clf_b (fused final)
  k_mm<3><<<dim3(1, BB * NN * NN / 128, 1), dim3(256), 0, stream>>>(
      gB, clfT, out, NC, WD, WD, NC, 0LL, 0LL, 0LL, nof, 0.f, rcW, clf_b);
}